// Round 1
// baseline (941.314 us; speedup 1.0000x reference)
//
#include <hip/hip_runtime.h>

typedef __bf16 bf16;
typedef __attribute__((ext_vector_type(8))) __bf16 bf16x8;
typedef __attribute__((ext_vector_type(4))) __bf16 bf16x4;
typedef __attribute__((ext_vector_type(4))) float floatx4;

#define LOG2E 1.4426950408889634f

// ---- async global->LDS (16B/lane, LDS dest = wave-uniform base + lane*16) ----
__device__ __forceinline__ void lds16(const void* g, void* l) {
  __builtin_amdgcn_global_load_lds(
      (const __attribute__((address_space(1))) unsigned int*)(unsigned long long)g,
      (__attribute__((address_space(3))) unsigned int*)(unsigned int)(unsigned long long)l,
      16, 0, 0);
}

// ================= GEMM: C[m,n] = sum_k A[m,k] * W[n,k]  (bf16 in, CT out) ====
// 128x128 tile, BK=32, 4 waves (2x2 of 64x64), 16x16x32 bf16 MFMA.
// LDS rows are 32 el (4 chunks of 8); chunk XOR-swizzled by ((row>>1)&3).
template <typename CT>
__global__ __launch_bounds__(256) void gemm_bt(const bf16* __restrict__ A,
                                               const bf16* __restrict__ W,
                                               CT* __restrict__ C,
                                               int M, int N, int K) {
  __shared__ bf16 sA[128 * 32];
  __shared__ bf16 sB[128 * 32];
  const int tid = threadIdx.x;
  const int lane = tid & 63;
  const int wave = tid >> 6;
  const int quad = lane >> 4;
  const int l16 = lane & 15;
  const int m0 = blockIdx.y * 128;
  const int n0 = blockIdx.x * 128;
  const int wm = (wave >> 1) * 64;
  const int wn = (wave & 1) * 64;

  floatx4 acc[4][4] = {};

  const int srow = tid >> 2;            // staging row (0..63), +64 on 2nd issue
  const int cs = tid & 3;
  const int clog = cs ^ ((srow >> 1) & 3);   // same for srow+64 (32%4==0)
  const bf16* gA = A + (long)(m0 + srow) * K + clog * 8;
  const bf16* gB = W + (long)(n0 + srow) * K + clog * 8;
  bf16* lA = sA + wave * 512;
  bf16* lB = sB + wave * 512;
  const long step64 = (long)64 * K;
  const int cq = quad ^ ((l16 >> 1) & 3);    // swizzled chunk for fragment reads

  for (int k0 = 0; k0 < K; k0 += 32) {
    lds16(gA, lA);
    lds16(gA + step64, lA + 2048);
    lds16(gB, lB);
    lds16(gB + step64, lB + 2048);
    gA += 32;
    gB += 32;
    __syncthreads();
    bf16x8 af[4], bfr[4];
#pragma unroll
    for (int i = 0; i < 4; ++i)
      af[i] = *(const bf16x8*)(sA + (wm + i * 16 + l16) * 32 + cq * 8);
#pragma unroll
    for (int j = 0; j < 4; ++j)
      bfr[j] = *(const bf16x8*)(sB + (wn + j * 16 + l16) * 32 + cq * 8);
#pragma unroll
    for (int i = 0; i < 4; ++i)
#pragma unroll
      for (int j = 0; j < 4; ++j)
        acc[i][j] = __builtin_amdgcn_mfma_f32_16x16x32_bf16(af[i], bfr[j], acc[i][j], 0, 0, 0);
    __syncthreads();
  }

#pragma unroll
  for (int i = 0; i < 4; ++i) {
    const int row = m0 + wm + i * 16 + quad * 4;
#pragma unroll
    for (int j = 0; j < 4; ++j) {
      const int col = n0 + wn + j * 16 + l16;
#pragma unroll
      for (int r = 0; r < 4; ++r)
        C[(long)(row + r) * N + col] = (CT)acc[i][j][r];
    }
  }
}

// ================= flash attention ==========================================
// grid (Q/128, H, B); block 256. Per wave: 32 q-rows x 128 kv.
// sK: K-tile then P-tile (reused); sV: V^T tile. 128-el rows, 16 chunks,
// chunk XOR-swizzled by (row&15).
__global__ __launch_bounds__(256, 2) void attn(const bf16* __restrict__ qr,
                                               const bf16* __restrict__ kc,
                                               const bf16* __restrict__ vt,
                                               const float* __restrict__ mask,
                                               const int* __restrict__ flag,
                                               bf16* __restrict__ o) {
  __shared__ bf16 sK[128 * 128];
  __shared__ bf16 sV[128 * 128];
  const int tid = threadIdx.x, lane = tid & 63, wave = tid >> 6;
  const int quad = lane >> 4, l16 = lane & 15;
  const int qt = blockIdx.x, h = blockIdx.y, b = blockIdx.z;
  const int kvh = h >> 2;
  const int q0 = qt * 128;

  // ---- stage Q tile (contiguous 128x128 bf16) into sK, swizzled ----
  const bf16* qbase = qr + ((long)(b * 32 + h) * 1024 + q0) * 128;
#pragma unroll
  for (int it = 0; it < 8; ++it) {
    const int row = (it * 4 + wave) * 4 + quad;
    const int cg = l16 ^ (row & 15);
    lds16(qbase + (long)row * 128 + cg * 8, sK + (it * 4 + wave) * 512);
  }
  __syncthreads();
  bf16x8 qf[2][4];
#pragma unroll
  for (int i = 0; i < 2; ++i)
#pragma unroll
    for (int ks = 0; ks < 4; ++ks)
      qf[i][ks] = *(const bf16x8*)(sK + (wave * 32 + i * 16 + l16) * 128 +
                                   (((ks * 4 + quad) ^ l16) * 8));
  __syncthreads();

  floatx4 oacc[2][8] = {};
  float mrun[2][4], lrun[2][4];
#pragma unroll
  for (int i = 0; i < 2; ++i)
#pragma unroll
    for (int r = 0; r < 4; ++r) { mrun[i][r] = -1e30f; lrun[i][r] = 0.f; }

  const float scale = 0.08838834764831845f;  // 1/sqrt(128)
  const bool use_mask = (*flag != 0);
  const bf16* kbase = kc + (long)(b * 8 + kvh) * 4096 * 128;
  const bf16* vbase = vt + (long)(b * 8 + kvh) * 128 * 4096;

  for (int kt = 0; kt < 32; ++kt) {
    const int kv0 = kt * 128;
    const bf16* kp = kbase + (long)kv0 * 128;
#pragma unroll
    for (int it = 0; it < 8; ++it) {   // K tile (contiguous in global)
      const int row = (it * 4 + wave) * 4 + quad;
      const int cg = l16 ^ (row & 15);
      lds16(kp + (long)row * 128 + cg * 8, sK + (it * 4 + wave) * 512);
    }
#pragma unroll
    for (int it = 0; it < 8; ++it) {   // V^T tile (rows stride KV in global)
      const int row = (it * 4 + wave) * 4 + quad;
      const int cg = l16 ^ (row & 15);
      lds16(vbase + (long)row * 4096 + kv0 + cg * 8, sV + (it * 4 + wave) * 512);
    }
    __syncthreads();

    // ---- S = Q K^T ----
    floatx4 s[2][8] = {};
#pragma unroll
    for (int ks = 0; ks < 4; ++ks) {
#pragma unroll
      for (int j = 0; j < 8; ++j) {
        const bf16x8 kf = *(const bf16x8*)(sK + (j * 16 + l16) * 128 +
                                           (((ks * 4 + quad) ^ l16) * 8));
        s[0][j] = __builtin_amdgcn_mfma_f32_16x16x32_bf16(qf[0][ks], kf, s[0][j], 0, 0, 0);
        s[1][j] = __builtin_amdgcn_mfma_f32_16x16x32_bf16(qf[1][ks], kf, s[1][j], 0, 0, 0);
      }
    }
#pragma unroll
    for (int i = 0; i < 2; ++i)
#pragma unroll
      for (int j = 0; j < 8; ++j)
#pragma unroll
        for (int r = 0; r < 4; ++r)
          s[i][j][r] *= scale;
    if (use_mask) {  // slow path (mask may be nonzero); never taken for zeros
#pragma unroll
      for (int i = 0; i < 2; ++i)
#pragma unroll
        for (int r = 0; r < 4; ++r) {
          const long mrow =
              ((long)b * 1024 + q0 + wave * 32 + i * 16 + quad * 4 + r) * 4096 + kv0;
#pragma unroll
          for (int j = 0; j < 8; ++j) s[i][j][r] += mask[mrow + j * 16 + l16];
        }
    }

    // ---- online softmax (rows live in quad-groups; 16 lanes cover 128 cols) ----
#pragma unroll
    for (int i = 0; i < 2; ++i)
#pragma unroll
      for (int r = 0; r < 4; ++r) {
        float mx = s[i][0][r];
#pragma unroll
        for (int j = 1; j < 8; ++j) mx = fmaxf(mx, s[i][j][r]);
        mx = fmaxf(mx, __shfl_xor(mx, 1, 64));
        mx = fmaxf(mx, __shfl_xor(mx, 2, 64));
        mx = fmaxf(mx, __shfl_xor(mx, 4, 64));
        mx = fmaxf(mx, __shfl_xor(mx, 8, 64));
        const float mnew = fmaxf(mrun[i][r], mx);
        const float alpha = exp2f((mrun[i][r] - mnew) * LOG2E);
        mrun[i][r] = mnew;
        lrun[i][r] *= alpha;
#pragma unroll
        for (int j = 0; j < 8; ++j) {
          oacc[i][j][r] *= alpha;
          const float p = exp2f((s[i][j][r] - mnew) * LOG2E);
          s[i][j][r] = p;
          lrun[i][r] += p;
        }
      }

    __syncthreads();  // all waves done reading K from sK
    // ---- P -> LDS ([q][kv], swizzled) ----
#pragma unroll
    for (int i = 0; i < 2; ++i)
#pragma unroll
      for (int j = 0; j < 8; ++j)
#pragma unroll
        for (int r = 0; r < 4; ++r) {
          const int row = wave * 32 + i * 16 + quad * 4 + r;
          const int ch = (j * 2 + (l16 >> 3)) ^ (row & 15);
          sK[row * 128 + ch * 8 + (l16 & 7)] = (bf16)s[i][j][r];
        }
    __syncthreads();

    // ---- O += P V ----
#pragma unroll
    for (int ks = 0; ks < 4; ++ks) {
      const bf16x8 pf0 = *(const bf16x8*)(sK + (wave * 32 + l16) * 128 +
                                          (((ks * 4 + quad) ^ l16) * 8));
      const bf16x8 pf1 = *(const bf16x8*)(sK + (wave * 32 + 16 + l16) * 128 +
                                          (((ks * 4 + quad) ^ l16) * 8));
#pragma unroll
      for (int j = 0; j < 8; ++j) {
        const bf16x8 vf = *(const bf16x8*)(sV + (j * 16 + l16) * 128 +
                                           (((ks * 4 + quad) ^ l16) * 8));
        oacc[0][j] = __builtin_amdgcn_mfma_f32_16x16x32_bf16(pf0, vf, oacc[0][j], 0, 0, 0);
        oacc[1][j] = __builtin_amdgcn_mfma_f32_16x16x32_bf16(pf1, vf, oacc[1][j], 0, 0, 0);
      }
    }
    __syncthreads();  // protect sK/sV before next staging
  }

  // ---- epilogue: O / l, write (B,Q,H,D) bf16 ----
#pragma unroll
  for (int i = 0; i < 2; ++i)
#pragma unroll
    for (int r = 0; r < 4; ++r) {
      float ls = lrun[i][r];
      ls += __shfl_xor(ls, 1, 64);
      ls += __shfl_xor(ls, 2, 64);
      ls += __shfl_xor(ls, 4, 64);
      ls += __shfl_xor(ls, 8, 64);
      const float inv = 1.f / ls;
      const int q = q0 + wave * 32 + i * 16 + quad * 4 + r;
      bf16* op = o + ((long)(b * 1024 + q) * 32 + h) * 128;
#pragma unroll
      for (int j = 0; j < 8; ++j) op[j * 16 + l16] = (bf16)(oacc[i][j][r] * inv);
    }
}

// ================= small prework kernels ====================================
__global__ void zeroflag(int* f) { *f = 0; }

__global__ void f2b4(const floatx4* __restrict__ in, bf16x4* __restrict__ out) {
  const long i = (long)blockIdx.x * 256 + threadIdx.x;
  const floatx4 v = in[i];
  bf16x4 o;
  o[0] = (bf16)v[0]; o[1] = (bf16)v[1]; o[2] = (bf16)v[2]; o[3] = (bf16)v[3];
  out[i] = o;
}

__global__ void maskchk(const floatx4* __restrict__ m, int* __restrict__ flag) {
  const long i = (long)blockIdx.x * 256 + threadIdx.x;
  const floatx4 v = m[i];
  if (v[0] != 0.f || v[1] != 0.f || v[2] != 0.f || v[3] != 0.f) atomicOr(flag, 1);
}

// cache_v (B*KVH, KV, D) fp32 -> vt (B*KVH, D, KV) bf16
__global__ void vtrans(const float* __restrict__ v, bf16* __restrict__ vt) {
  __shared__ float t[32][33];
  const int bk = blockIdx.z;
  const int kv0 = blockIdx.x * 32, d0 = blockIdx.y * 32;
  const int tx = threadIdx.x, ty = threadIdx.y;
  const float* src = v + ((long)bk * 4096 + kv0) * 128 + d0;
#pragma unroll
  for (int k = 0; k < 4; ++k) t[ty * 4 + k][tx] = src[(ty * 4 + k) * 128 + tx];
  __syncthreads();
  bf16* dst = vt + ((long)bk * 128 + d0) * 4096 + kv0;
#pragma unroll
  for (int k = 0; k < 4; ++k) dst[(ty * 4 + k) * 4096 + tx] = (bf16)t[tx][ty * 4 + k];
}

// qkv (M,6144) bf16; q part -> RoPE -> q_rope (B,H,Q,D) bf16
__global__ void rope_q(const bf16* __restrict__ qkv, const float* __restrict__ cosp,
                       const float* __restrict__ sinp, bf16* __restrict__ qrope) {
  const long idx = (long)blockIdx.x * 256 + threadIdx.x;  // ((b*32+h)*1024+q)*128+d
  const int d = (int)idx & 127;
  const int q = (int)(idx >> 7) & 1023;
  const int h = (int)(idx >> 17) & 31;
  const int b = (int)(idx >> 22);
  const long qrow = ((long)b * 1024 + q) * 6144 + h * 128;
  const float x = (float)qkv[qrow + d];
  const float y = (float)qkv[qrow + (d ^ 64)];
  const long ci = ((long)b * 1024 + q) * 128 + d;
  const float rh = (d < 64) ? -y : y;
  qrope[idx] = (bf16)(x * cosp[ci] + rh * sinp[ci]);
}

// k part -> RoPE -> scatter into kc (B,KVH,KV,D) bf16 at sink rows
__global__ void rope_k(const bf16* __restrict__ qkv, const float* __restrict__ cosp,
                       const float* __restrict__ sinp, const int* __restrict__ sink,
                       bf16* __restrict__ kcb) {
  const long idx = (long)blockIdx.x * 256 + threadIdx.x;  // ((b*1024+q)*8+kvh)*128+d
  const int d = (int)idx & 127;
  const int kvh = (int)(idx >> 7) & 7;
  const int q = (int)(idx >> 10) & 1023;
  const int b = (int)(idx >> 20);
  const long krow = ((long)b * 1024 + q) * 6144 + 4096 + kvh * 128;
  const float x = (float)qkv[krow + d];
  const float y = (float)qkv[krow + (d ^ 64)];
  const long ci = ((long)b * 1024 + q) * 128 + d;
  const float rh = (d < 64) ? -y : y;
  const int sk = sink[q];
  kcb[(((long)b * 8 + kvh) * 4096 + sk) * 128 + d] = (bf16)(x * cosp[ci] + rh * sinp[ci]);
}

// v part -> scatter into vt (B,KVH,D,KV) bf16 at sink columns
__global__ void scat_v(const bf16* __restrict__ qkv, const int* __restrict__ sink,
                       bf16* __restrict__ vtb) {
  const long idx = (long)blockIdx.x * 256 + threadIdx.x;  // (((b*8+kvh)*128+d)*1024+q)
  const int q = (int)idx & 1023;
  const int d = (int)(idx >> 10) & 127;
  const int kvh = (int)(idx >> 17) & 7;
  const int b = (int)(idx >> 20);
  const int sk = sink[q];
  const bf16 val = qkv[((long)b * 1024 + q) * 6144 + 5120 + kvh * 128 + d];
  vtb[(((long)b * 8 + kvh) * 128 + d) * 4096 + sk] = val;
}

// ================= launcher =================================================
extern "C" void kernel_launch(void* const* d_in, const int* in_sizes, int n_in,
                              void* d_out, int out_size, void* d_ws, size_t ws_size,
                              hipStream_t stream) {
  const float* hid  = (const float*)d_in[0];
  const float* cosp = (const float*)d_in[1];
  const float* sinp = (const float*)d_in[2];
  const float* mask = (const float*)d_in[3];
  const float* ck   = (const float*)d_in[4];
  const float* cv   = (const float*)d_in[5];
  const int*   sink = (const int*)d_in[6];
  const float* Wq   = (const float*)d_in[7];
  const float* Wk   = (const float*)d_in[8];
  const float* Wv   = (const float*)d_in[9];
  const float* Wo   = (const float*)d_in[10];
  float* out = (float*)d_out;

  char* ws = (char*)d_ws;
  bf16* wqkv  = (bf16*)(ws);                 // 6144*4096*2      = 50331648
  bf16* hidb  = (bf16*)(ws + 50331648);      // 2048*4096*2      = 16777216
  bf16* qkvb  = (bf16*)(ws + 67108864);      // 2048*6144*2      = 25165824
  bf16* qrope = (bf16*)(ws + 92274688);      // 16777216
  bf16* kcb   = (bf16*)(ws + 109051904);     // 16777216
  bf16* vtb   = (bf16*)(ws + 125829120);     // 16777216
  bf16* ob    = (bf16*)(ws + 142606336);     // 16777216
  int*  flag  = (int*)(ws + 159383552);
  bf16* wob   = (bf16*)(ws + 50331648);      // overlay hidb+qkvb (dead by then)

  zeroflag<<<1, 1, 0, stream>>>(flag);

  // fp32 -> bf16 conversions
  f2b4<<<8192, 256, 0, stream>>>((const floatx4*)hid, (bf16x4*)hidb);
  f2b4<<<16384, 256, 0, stream>>>((const floatx4*)Wq, (bf16x4*)wqkv);
  f2b4<<<4096, 256, 0, stream>>>((const floatx4*)Wk, (bf16x4*)(wqkv + 16777216));
  f2b4<<<4096, 256, 0, stream>>>((const floatx4*)Wv, (bf16x4*)(wqkv + 20971520));
  f2b4<<<8192, 256, 0, stream>>>((const floatx4*)ck, (bf16x4*)kcb);
  maskchk<<<8192, 256, 0, stream>>>((const floatx4*)mask, flag);
  vtrans<<<dim3(128, 4, 16), dim3(32, 8), 0, stream>>>(cv, vtb);

  // fused QKV projection: (2048x4096) @ (6144x4096)^T -> (2048x6144) bf16
  gemm_bt<bf16><<<dim3(48, 16), 256, 0, stream>>>(hidb, wqkv, qkvb, 2048, 6144, 4096);

  rope_q<<<32768, 256, 0, stream>>>(qkvb, cosp, sinp, qrope);
  rope_k<<<8192, 256, 0, stream>>>(qkvb, cosp, sinp, sink, kcb);
  scat_v<<<8192, 256, 0, stream>>>(qkvb, sink, vtb);

  // Wo conversion (overlays hidb/qkvb which are dead now)
  f2b4<<<16384, 256, 0, stream>>>((const floatx4*)Wo, (bf16x4*)wob);

  attn<<<dim3(8, 32, 2), 256, 0, stream>>>(qrope, kcb, vtb, mask, flag, ob);

  // output projection: (2048x4096) @ (4096x4096)^T -> fp32 out
  gemm_bt<float><<<dim3(32, 16), 256, 0, stream>>>(ob, wob, out, 2048, 4096, 4096);

  (void)in_sizes; (void)n_in; (void)out_size; (void)ws_size;
}